// Round 4
// baseline (255.386 us; speedup 1.0000x reference)
//
#include <hip/hip_runtime.h>

#define NB 512
#define NG 100
#define NP 100
#define NE 128
#define NH 8

typedef __attribute__((ext_vector_type(8))) short short8;
typedef __attribute__((ext_vector_type(4))) short short4v;
typedef __attribute__((ext_vector_type(4))) float f32x4;

// LDS geometry: all bf16(short) row-major, XOR-swizzled per row.
// element (row,col) -> physical short offset: (row*STRIDE + col) ^ ((row&15)<<2)
// Injectivity: rows start at multiples of 16; adjacent-row swizzle diffs are
// {4,12} within shared 64-windows -> 16-block-closed -> bijective. (verified)
#define SE_STRIDE 128
#define SK_STRIDE 128
#define SVT_STRIDE 112
#define SE_BASE 0
#define SK_BASE (100 * 128)                  // 12800 shorts
#define SVT_BASE (SK_BASE + 100 * 128)       // 25600 shorts
#define SMEM_SHORTS (SVT_BASE + 128 * 112)   // 39936 shorts
#define SMEM_BYTES (SMEM_SHORTS * 2)         // 79872 B -> 2 blocks/CU (159744 <= 163840)

__device__ __forceinline__ short f2bf(float f) {
    union { float f; unsigned u; } v; v.f = f;
    unsigned r = v.u + 0x7FFFu + ((v.u >> 16) & 1u);
    return (short)(r >> 16);
}

__device__ __forceinline__ f32x4 mfma16(short4v a, short4v b, f32x4 c) {
#if __has_builtin(__builtin_amdgcn_mfma_f32_16x16x16_bf16)
    return __builtin_amdgcn_mfma_f32_16x16x16_bf16(a, b, c, 0, 0, 0);
#elif __has_builtin(__builtin_amdgcn_mfma_f32_16x16x16bf16_1k)
    return __builtin_amdgcn_mfma_f32_16x16x16bf16_1k(a, b, c, 0, 0, 0);
#else
    f32x4 d;
    asm volatile("v_mfma_f32_16x16x16_bf16 %0, %1, %2, %3"
                 : "=&v"(d) : "v"(a), "v"(b), "v"(c));
    return d;
#endif
}

__device__ __forceinline__ f32x4 mfma32(short8 a, short8 b, f32x4 c) {
    return __builtin_amdgcn_mfma_f32_16x16x32_bf16(a, b, c, 0, 0, 0);
}

// ---- prep: transpose weights to bf16 row-major [n][k] in ws (5 matrices) ----
__global__ void prep_kernel(const float* __restrict__ Wq, const float* __restrict__ Wk,
                            const float* __restrict__ Wv, const float* __restrict__ Wc,
                            short* __restrict__ WqT2, short* __restrict__ WkT,
                            short* __restrict__ WvT, short* __restrict__ WcT,
                            short* __restrict__ WqT1)
{
    int idx = blockIdx.x * 256 + threadIdx.x;   // 81920 total
    int mat = idx >> 14;
    int e   = idx & 16383;
    int k = e >> 7, n = e & 127;
    float v;
    short* dst;
    if (mat == 0)      { v = Wq[(128 + k) * 128 + n]; dst = WqT2; }
    else if (mat == 1) { v = Wk[k * 128 + n];         dst = WkT;  }
    else if (mat == 2) { v = Wv[k * 128 + n];         dst = WvT;  }
    else if (mat == 3) { v = Wc[k * 128 + n];         dst = WcT;  }
    else               { v = Wq[k * 128 + n];         dst = WqT1; }
    dst[n * 128 + k] = f2bf(v);
}

// ---- fused main kernel: one block per batch, 7 waves, everything transposed ----
__global__ __launch_bounds__(448, 2)
void fused_kernel(const float* __restrict__ input1, const float* __restrict__ input2,
                  const float* __restrict__ rem, const float* __restrict__ mask,
                  const float* __restrict__ enc, const float* __restrict__ Wq,
                  const float* __restrict__ bc,
                  const short* __restrict__ WqT2, const short* __restrict__ WkT,
                  const short* __restrict__ WvT, const short* __restrict__ WcT,
                  const short* __restrict__ WqT1, float* __restrict__ out)
{
    extern __shared__ short smem[];

    const int b    = blockIdx.x;
    const int tid  = threadIdx.x;
    const int wave = tid >> 6, lane = tid & 63;
    const int l16  = lane & 15, lh = lane >> 4;
    const int gt   = wave;                        // 7 waves, 7 g-tiles
    const int g    = gt * 16 + l16;
    const bool gok = (g < NG);
    const float NINF = -__builtin_inff();

    // ---------- Phase 0: stage enc -> sE (swizzled bf16), zero sVT pad ----------
    {
        const f32x4* e4 = (const f32x4*)(enc + (size_t)b * NP * NE);
        for (int idx = tid; idx < NP * 32; idx += 448) {
            int row = idx >> 5, c = idx & 31;
            f32x4 v = e4[idx];
            short4v h = { f2bf(v[0]), f2bf(v[1]), f2bf(v[2]), f2bf(v[3]) };
            int off = (row * SE_STRIDE + c * 4) ^ ((row & 15) << 2);
            *(short4v*)(smem + SE_BASE + off) = h;
        }
        // zero V^T cols 100..111 (never written afterwards)
        for (int idx = tid; idx < 128 * 3; idx += 448) {
            int row = idx / 3, c = 100 + (idx % 3) * 4;
            int off = (row * SVT_STRIDE + c) ^ ((row & 15) << 2);
            *(short4v*)(smem + SVT_BASE + off) = (short4v){0, 0, 0, 0};
        }
    }

    // ---------- Phase 1: Q^T into regs (x32, input1 folded), no LDS ----------
    short4v qb[8];
    {
        const float* xrow = input2 + ((size_t)b * NG + g) * NE;
        const float* i1   = input1 + (size_t)b * NE;
        short8 xb[4], yb[4];
        #pragma unroll
        for (int ks = 0; ks < 4; ++ks) {
            f32x4 v0 = {0.f,0.f,0.f,0.f}, v1 = {0.f,0.f,0.f,0.f};
            if (gok) {
                v0 = *(const f32x4*)(xrow + ks * 32 + lh * 8);
                v1 = *(const f32x4*)(xrow + ks * 32 + lh * 8 + 4);
            }
            xb[ks] = (short8){ f2bf(v0[0]), f2bf(v0[1]), f2bf(v0[2]), f2bf(v0[3]),
                               f2bf(v1[0]), f2bf(v1[1]), f2bf(v1[2]), f2bf(v1[3]) };
            f32x4 u0 = *(const f32x4*)(i1 + ks * 32 + lh * 8);
            f32x4 u1 = *(const f32x4*)(i1 + ks * 32 + lh * 8 + 4);
            yb[ks] = (short8){ f2bf(u0[0]), f2bf(u0[1]), f2bf(u0[2]), f2bf(u0[3]),
                               f2bf(u1[0]), f2bf(u1[1]), f2bf(u1[2]), f2bf(u1[3]) };
        }
        float remv = gok ? rem[(size_t)b * NG + g] : 0.f;
        #pragma unroll
        for (int nt = 0; nt < 8; ++nt) {
            f32x4 acc0 = {0.f, 0.f, 0.f, 0.f}, acc1 = {0.f, 0.f, 0.f, 0.f};
            #pragma unroll
            for (int ks = 0; ks < 4; ++ks) {
                short8 a2 = *(const short8*)(WqT2 + (nt * 16 + l16) * NE + ks * 32 + lh * 8);
                acc0 = mfma32(a2, xb[ks], acc0);
                short8 a1 = *(const short8*)(WqT1 + (nt * 16 + l16) * NE + ks * 32 + lh * 8);
                acc1 = mfma32(a1, yb[ks], acc1);
            }
            f32x4 wlv = *(const f32x4*)(Wq + 256 * NE + nt * 16 + lh * 4);
            short4v q;
            #pragma unroll
            for (int r = 0; r < 4; ++r)
                q[r] = f2bf(0.25f * (acc0[r] + acc1[r] + remv * wlv[r]));
            qb[nt] = q;
        }
    }
    __syncthreads();

    // ---------- Phase 2: K -> sK, V^T -> sVT (112 tile-tasks over 7 waves) ----------
    for (int t = wave; t < 112; t += 7) {
        int mat = (t >= 56);
        int tt  = mat ? t - 56 : t;
        int mt = tt >> 3, nt = tt & 7;
        const short* WT = mat ? WvT : WkT;
        int arow = mt * 16 + l16;
        bool aok = (arow < NP);
        f32x4 acc0 = {0.f, 0.f, 0.f, 0.f}, acc1 = {0.f, 0.f, 0.f, 0.f};
        #pragma unroll
        for (int kt = 0; kt < 8; ++kt) {
            short4v a = {0, 0, 0, 0};
            if (aok) {
                int off = (arow * SE_STRIDE + kt * 16 + lh * 4) ^ ((arow & 15) << 2);
                a = *(const short4v*)(smem + SE_BASE + off);
            }
            short4v w = *(const short4v*)(WT + (nt * 16 + l16) * NE + kt * 16 + lh * 4);
            if (kt < 4) acc0 = mfma16(a, w, acc0);
            else        acc1 = mfma16(a, w, acc1);
        }
        f32x4 acc = acc0 + acc1;
        if (!mat) {
            #pragma unroll
            for (int r = 0; r < 4; ++r) {
                int p = mt * 16 + lh * 4 + r;
                if (p < NP) {
                    int off = (p * SK_STRIDE + nt * 16 + l16) ^ ((p & 15) << 2);
                    smem[SK_BASE + off] = f2bf(acc[r]);
                }
            }
        } else {
            int vrow = nt * 16 + l16;          // k-dim 0..127
            int p0 = mt * 16 + lh * 4;
            if (p0 < NP) {
                short4v h = { f2bf(acc[0]), f2bf(acc[1]), f2bf(acc[2]), f2bf(acc[3]) };
                int off = (vrow * SVT_STRIDE + p0) ^ ((vrow & 15) << 2);
                *(short4v*)(smem + SVT_BASE + off) = h;
            }
        }
    }

    // ---------- mask preload (latency hidden by barrier wait) ----------
    float mk[7][4];
    {
        const float* mrow = mask + ((size_t)b * NG + g) * NP;
        #pragma unroll
        for (int pt = 0; pt < 7; ++pt)
            #pragma unroll
            for (int r = 0; r < 4; ++r) {
                int p = pt * 16 + lh * 4 + r;
                mk[pt][r] = (gok && p < NP) ? mrow[p] : NINF;
            }
    }
    __syncthreads();

    // ---------- Phase 3: attention, all-register online path ----------
    short4v ocb[8];
    #pragma unroll
    for (int h = 0; h < NH; ++h) {
        float vals[7][4];
        #pragma unroll
        for (int pt = 0; pt < 7; ++pt) {
            int prow = pt * 16 + l16;
            int off = (prow * SK_STRIDE + h * 16 + lh * 4) ^ ((prow & 15) << 2);
            short4v kf = *(const short4v*)(smem + SK_BASE + off);
            f32x4 z = {0.f, 0.f, 0.f, 0.f};
            f32x4 sc = mfma16(kf, qb[h], z);
            bool pv = (pt < 6) || (lh == 0);   // p < 100
            #pragma unroll
            for (int r = 0; r < 4; ++r)
                vals[pt][r] = pv ? sc[r] + mk[pt][r] : NINF;
        }
        // max: 4 parallel chains + tree
        float mr0 = vals[0][0], mr1 = vals[0][1], mr2 = vals[0][2], mr3 = vals[0][3];
        #pragma unroll
        for (int pt = 1; pt < 7; ++pt) {
            mr0 = fmaxf(mr0, vals[pt][0]); mr1 = fmaxf(mr1, vals[pt][1]);
            mr2 = fmaxf(mr2, vals[pt][2]); mr3 = fmaxf(mr3, vals[pt][3]);
        }
        float m = fmaxf(fmaxf(mr0, mr1), fmaxf(mr2, mr3));
        m = fmaxf(m, __shfl_xor(m, 16));
        m = fmaxf(m, __shfl_xor(m, 32));
        // exp + sum: 4 parallel chains + tree
        float s0 = 0.f, s1 = 0.f, s2 = 0.f, s3 = 0.f;
        #pragma unroll
        for (int pt = 0; pt < 7; ++pt) {
            float e0 = __expf(vals[pt][0] - m); vals[pt][0] = e0; s0 += e0;
            float e1 = __expf(vals[pt][1] - m); vals[pt][1] = e1; s1 += e1;
            float e2 = __expf(vals[pt][2] - m); vals[pt][2] = e2; s2 += e2;
            float e3 = __expf(vals[pt][3] - m); vals[pt][3] = e3; s3 += e3;
        }
        float s = (s0 + s1) + (s2 + s3);
        s += __shfl_xor(s, 16);
        s += __shfl_xor(s, 32);
        float inv = 1.f / s;
        // PV: two accumulate chains (4 + 3)
        f32x4 o0 = {0.f, 0.f, 0.f, 0.f}, o1 = {0.f, 0.f, 0.f, 0.f};
        #pragma unroll
        for (int pt = 0; pt < 7; ++pt) {
            short4v pb = { f2bf(vals[pt][0] * inv), f2bf(vals[pt][1] * inv),
                           f2bf(vals[pt][2] * inv), f2bf(vals[pt][3] * inv) };
            int vrow = h * 16 + l16;
            int off = (vrow * SVT_STRIDE + pt * 16 + lh * 4) ^ ((vrow & 15) << 2);
            short4v vf = *(const short4v*)(smem + SVT_BASE + off);
            if (pt & 1) o1 = mfma16(vf, pb, o1);
            else        o0 = mfma16(vf, pb, o0);
        }
        f32x4 o = o0 + o1;
        ocb[h] = (short4v){ f2bf(o[0]), f2bf(o[1]), f2bf(o[2]), f2bf(o[3]) };
    }

    // ---------- Phase 4: Mh^T = Wc^T . oc^T + bc, fold 1/sqrt(128), pack ----------
    short4v mhb[8];
    #pragma unroll
    for (int nt = 0; nt < 8; ++nt) {
        f32x4 acc0 = {0.f, 0.f, 0.f, 0.f}, acc1 = {0.f, 0.f, 0.f, 0.f};
        #pragma unroll
        for (int kt = 0; kt < 8; ++kt) {
            short4v a = *(const short4v*)(WcT + (nt * 16 + l16) * NE + kt * 16 + lh * 4);
            if (kt < 4) acc0 = mfma16(a, ocb[kt], acc0);
            else        acc1 = mfma16(a, ocb[kt], acc1);
        }
        f32x4 acc = acc0 + acc1;
        f32x4 bcv = *(const f32x4*)(bc + nt * 16 + lh * 4);
        mhb[nt] = (short4v){ f2bf((acc[0] + bcv[0]) * 0.08838834764831845f),
                             f2bf((acc[1] + bcv[1]) * 0.08838834764831845f),
                             f2bf((acc[2] + bcv[2]) * 0.08838834764831845f),
                             f2bf((acc[3] + bcv[3]) * 0.08838834764831845f) };
    }

    // ---------- Phase 5: pointer scores + tanh clip + softmax -> out ----------
    const float* mrow = mask + ((size_t)b * NG + g) * NP;
    float vals2[7][4];
    #pragma unroll
    for (int pt = 0; pt < 7; ++pt) {
        int prow = pt * 16 + l16;
        f32x4 acc0 = {0.f, 0.f, 0.f, 0.f}, acc1 = {0.f, 0.f, 0.f, 0.f};
        #pragma unroll
        for (int kt = 0; kt < 8; ++kt) {
            int off = (prow * SE_STRIDE + kt * 16 + lh * 4) ^ ((prow & 15) << 2);
            short4v ef = *(const short4v*)(smem + SE_BASE + off);
            if (kt < 4) acc0 = mfma16(ef, mhb[kt], acc0);
            else        acc1 = mfma16(ef, mhb[kt], acc1);
        }
        f32x4 acc = acc0 + acc1;
        #pragma unroll
        for (int r = 0; r < 4; ++r) {
            int p = pt * 16 + lh * 4 + r;
            bool pv = gok && (p < NP);
            float mkv = pv ? mrow[p] : NINF;
            float x = acc[r];                              // already scaled
            float th = 1.f - 2.f / (__expf(2.f * x) + 1.f);
            vals2[pt][r] = pv ? 10.f * th + mkv : NINF;
        }
    }
    {
        float mr0 = vals2[0][0], mr1 = vals2[0][1], mr2 = vals2[0][2], mr3 = vals2[0][3];
        #pragma unroll
        for (int pt = 1; pt < 7; ++pt) {
            mr0 = fmaxf(mr0, vals2[pt][0]); mr1 = fmaxf(mr1, vals2[pt][1]);
            mr2 = fmaxf(mr2, vals2[pt][2]); mr3 = fmaxf(mr3, vals2[pt][3]);
        }
        float m = fmaxf(fmaxf(mr0, mr1), fmaxf(mr2, mr3));
        m = fmaxf(m, __shfl_xor(m, 16));
        m = fmaxf(m, __shfl_xor(m, 32));
        float s0 = 0.f, s1 = 0.f, s2 = 0.f, s3 = 0.f;
        #pragma unroll
        for (int pt = 0; pt < 7; ++pt) {
            float e0 = __expf(vals2[pt][0] - m); vals2[pt][0] = e0; s0 += e0;
            float e1 = __expf(vals2[pt][1] - m); vals2[pt][1] = e1; s1 += e1;
            float e2 = __expf(vals2[pt][2] - m); vals2[pt][2] = e2; s2 += e2;
            float e3 = __expf(vals2[pt][3] - m); vals2[pt][3] = e3; s3 += e3;
        }
        float s = (s0 + s1) + (s2 + s3);
        s += __shfl_xor(s, 16);
        s += __shfl_xor(s, 32);
        float inv = 1.f / s;
        float* orow = out + ((size_t)b * NG + g) * NP;
        #pragma unroll
        for (int pt = 0; pt < 7; ++pt)
            #pragma unroll
            for (int r = 0; r < 4; ++r) {
                int p = pt * 16 + lh * 4 + r;
                if (gok && p < NP) orow[p] = vals2[pt][r] * inv;
            }
    }
}

extern "C" void kernel_launch(void* const* d_in, const int* in_sizes, int n_in,
                              void* d_out, int out_size, void* d_ws, size_t ws_size,
                              hipStream_t stream)
{
    const float* input1 = (const float*)d_in[0];
    const float* input2 = (const float*)d_in[1];
    const float* rem    = (const float*)d_in[2];
    const float* mask   = (const float*)d_in[3];
    const float* enc    = (const float*)d_in[4];
    const float* Wq     = (const float*)d_in[5];
    const float* Wk     = (const float*)d_in[6];
    const float* Wv     = (const float*)d_in[7];
    const float* Wc     = (const float*)d_in[8];
    const float* bc     = (const float*)d_in[9];

    short* WqT2 = (short*)d_ws;
    short* WkT  = WqT2 + 16384;
    short* WvT  = WkT + 16384;
    short* WcT  = WvT + 16384;
    short* WqT1 = WcT + 16384;

    prep_kernel<<<320, 256, 0, stream>>>(Wq, Wk, Wv, Wc, WqT2, WkT, WvT, WcT, WqT1);

    hipFuncSetAttribute((const void*)fused_kernel,
                        hipFuncAttributeMaxDynamicSharedMemorySize, SMEM_BYTES);
    fused_kernel<<<NB, 448, SMEM_BYTES, stream>>>(
        input1, input2, rem, mask, enc, Wq, bc,
        WqT2, WkT, WvT, WcT, WqT1, (float*)d_out);
}

// Round 5
// 217.178 us; speedup vs baseline: 1.1759x; 1.1759x over previous
//
#include <hip/hip_runtime.h>

#define NB 512
#define NG 100
#define NP 100
#define NE 128
#define NH 8

typedef __attribute__((ext_vector_type(8))) short short8;
typedef __attribute__((ext_vector_type(4))) short short4v;
typedef __attribute__((ext_vector_type(4))) float f32x4;

__device__ __forceinline__ short f2bf(float f) {
    union { float f; unsigned u; } v; v.f = f;
    unsigned r = v.u + 0x7FFFu + ((v.u >> 16) & 1u);
    return (short)(r >> 16);
}

__device__ __forceinline__ f32x4 mfma16(short4v a, short4v b, f32x4 c) {
#if __has_builtin(__builtin_amdgcn_mfma_f32_16x16x16_bf16)
    return __builtin_amdgcn_mfma_f32_16x16x16_bf16(a, b, c, 0, 0, 0);
#elif __has_builtin(__builtin_amdgcn_mfma_f32_16x16x16bf16_1k)
    return __builtin_amdgcn_mfma_f32_16x16x16bf16_1k(a, b, c, 0, 0, 0);
#else
    f32x4 d;
    asm volatile("v_mfma_f32_16x16x16_bf16 %0, %1, %2, %3"
                 : "=&v"(d) : "v"(a), "v"(b), "v"(c));
    return d;
#endif
}

__device__ __forceinline__ f32x4 mfma32(short8 a, short8 b, f32x4 c) {
    return __builtin_amdgcn_mfma_f32_16x16x32_bf16(a, b, c, 0, 0, 0);
}

// ---- prep: weights -> bf16, transposed [n][k]; Wc -> fragment-blocked ----
__global__ void prep_kernel(const float* __restrict__ Wq, const float* __restrict__ Wk,
                            const float* __restrict__ Wv, const float* __restrict__ Wc,
                            short* __restrict__ WqT2, short* __restrict__ WkT,
                            short* __restrict__ WvT, short* __restrict__ WqT1,
                            short* __restrict__ WcB)
{
    int idx = blockIdx.x * 256 + threadIdx.x;   // 81920 total
    int mat = idx >> 14;
    int e   = idx & 16383;
    int k = e >> 7, n = e & 127;
    if (mat == 0)      WqT2[n * 128 + k] = f2bf(Wq[(128 + k) * 128 + n]);
    else if (mat == 1) WkT [n * 128 + k] = f2bf(Wk[k * 128 + n]);
    else if (mat == 2) WvT [n * 128 + k] = f2bf(Wv[k * 128 + n]);
    else if (mat == 3)
        // blockedWc[nt][kt][i=n&15][c=k&15] = Wc^T[n][k]
        WcB[(((n >> 4) << 3) + (k >> 4)) * 256 + ((n & 15) << 4) + (k & 15)] = f2bf(Wc[k * 128 + n]);
    else               WqT1[n * 128 + k] = f2bf(Wq[k * 128 + n]);
}

// ---- fused main kernel: one block per batch, 7 waves ----
// LDS holds ONLY K and V^T, in MFMA-fragment-blocked layout:
//   sK[h][pt][i][c] = K[pt*16+i][h*16+c]      (kf read = wave-contiguous 512B)
//   sV[h][pt][i][c] = V^T[h*16+i][pt*16+c]    (vf read = wave-contiguous 512B)
__global__ __launch_bounds__(448, 2)
void fused_kernel(const float* __restrict__ input1, const float* __restrict__ input2,
                  const float* __restrict__ rem, const float* __restrict__ mask,
                  const float* __restrict__ enc, const float* __restrict__ Wq,
                  const float* __restrict__ bc,
                  const short* __restrict__ WqT2, const short* __restrict__ WkT,
                  const short* __restrict__ WvT, const short* __restrict__ WqT1,
                  const short* __restrict__ WcB, float* __restrict__ out)
{
    __shared__ short sKV[2 * 56 * 256];          // 57,344 B total
    short* sK = sKV;
    short* sV = sKV + 56 * 256;

    const int b    = blockIdx.x;
    const int tid  = threadIdx.x;
    const int wave = tid >> 6, lane = tid & 63;
    const int l16  = lane & 15, lh = lane >> 4;
    const int g    = wave * 16 + l16;
    const bool gok = (g < NG);
    const float NINF = -__builtin_inff();

    // ---------- Phase 1: Q^T into regs (input1 folded), scale 1/4, pack bf16 ----------
    short4v qb[8];
    {
        const float* xrow = input2 + ((size_t)b * NG + g) * NE;
        const float* i1   = input1 + (size_t)b * NE;
        short8 xb[4], yb[4];
        #pragma unroll
        for (int ks = 0; ks < 4; ++ks) {
            f32x4 v0 = {0.f,0.f,0.f,0.f}, v1 = {0.f,0.f,0.f,0.f};
            if (gok) {
                v0 = *(const f32x4*)(xrow + ks * 32 + lh * 8);
                v1 = *(const f32x4*)(xrow + ks * 32 + lh * 8 + 4);
            }
            xb[ks] = (short8){ f2bf(v0[0]), f2bf(v0[1]), f2bf(v0[2]), f2bf(v0[3]),
                               f2bf(v1[0]), f2bf(v1[1]), f2bf(v1[2]), f2bf(v1[3]) };
            f32x4 u0 = *(const f32x4*)(i1 + ks * 32 + lh * 8);
            f32x4 u1 = *(const f32x4*)(i1 + ks * 32 + lh * 8 + 4);
            yb[ks] = (short8){ f2bf(u0[0]), f2bf(u0[1]), f2bf(u0[2]), f2bf(u0[3]),
                               f2bf(u1[0]), f2bf(u1[1]), f2bf(u1[2]), f2bf(u1[3]) };
        }
        float remv = gok ? rem[(size_t)b * NG + g] : 0.f;
        #pragma unroll
        for (int nt = 0; nt < 8; ++nt) {
            f32x4 acc0 = {0.f, 0.f, 0.f, 0.f}, acc1 = {0.f, 0.f, 0.f, 0.f};
            #pragma unroll
            for (int ks = 0; ks < 4; ++ks) {
                short8 a2 = *(const short8*)(WqT2 + (nt * 16 + l16) * NE + ks * 32 + lh * 8);
                acc0 = mfma32(a2, xb[ks], acc0);
                short8 a1 = *(const short8*)(WqT1 + (nt * 16 + l16) * NE + ks * 32 + lh * 8);
                acc1 = mfma32(a1, yb[ks], acc1);
            }
            f32x4 wlv = *(const f32x4*)(Wq + 256 * NE + nt * 16 + lh * 4);
            short4v q;
            #pragma unroll
            for (int r = 0; r < 4; ++r)
                q[r] = f2bf(0.25f * (acc0[r] + acc1[r] + remv * wlv[r]));
            qb[nt] = q;
        }
    }

    // ---------- Phase 2: K and V^T -> LDS (blocked frag layout) ----------
    // Wave w loads enc rows w*16+l16 ONCE; same per-lane data is A-frag for
    // K-tiles (row = l16) and B-frag for V^T-tiles (col p = l16).
    {
        int row = wave * 16 + l16;
        int rc  = row < NP ? row : NP - 1;          // clamp (finite garbage ok)
        const float* er = enc + ((size_t)b * NP + rc) * NE;
        short8 eb[4];
        #pragma unroll
        for (int ks = 0; ks < 4; ++ks) {
            f32x4 u0 = *(const f32x4*)(er + ks * 32 + lh * 8);
            f32x4 u1 = *(const f32x4*)(er + ks * 32 + lh * 8 + 4);
            eb[ks] = (short8){ f2bf(u0[0]), f2bf(u0[1]), f2bf(u0[2]), f2bf(u0[3]),
                               f2bf(u1[0]), f2bf(u1[1]), f2bf(u1[2]), f2bf(u1[3]) };
        }
        #pragma unroll
        for (int h = 0; h < NH; ++h) {              // K tiles (mt = wave, nt = h)
            f32x4 a0 = {0.f,0.f,0.f,0.f}, a1 = {0.f,0.f,0.f,0.f};
            #pragma unroll
            for (int ks = 0; ks < 4; ++ks) {
                short8 w = *(const short8*)(WkT + (h * 16 + l16) * NE + ks * 32 + lh * 8);
                if (ks < 2) a0 = mfma32(eb[ks], w, a0);
                else        a1 = mfma32(eb[ks], w, a1);
            }
            f32x4 acc = a0 + a1;
            int base = (h * 7 + wave) * 256;
            #pragma unroll
            for (int r = 0; r < 4; ++r)
                sK[base + (lh * 4 + r) * 16 + l16] = f2bf(acc[r]);
        }
        #pragma unroll
        for (int kb = 0; kb < 8; ++kb) {            // V^T tiles (kb, pt = wave)
            f32x4 a0 = {0.f,0.f,0.f,0.f}, a1 = {0.f,0.f,0.f,0.f};
            #pragma unroll
            for (int ks = 0; ks < 4; ++ks) {
                short8 a = *(const short8*)(WvT + (kb * 16 + l16) * NE + ks * 32 + lh * 8);
                if (ks < 2) a0 = mfma32(a, eb[ks], a0);
                else        a1 = mfma32(a, eb[ks], a1);
            }
            f32x4 acc = a0 + a1;
            int base = (kb * 7 + wave) * 256;
            bool pz = (wave == 6) && (l16 >= 4);    // p >= 100: MUST be zero (PV safety)
            #pragma unroll
            for (int r = 0; r < 4; ++r)
                sV[base + (lh * 4 + r) * 16 + l16] = pz ? (short)0 : f2bf(acc[r]);
        }
    }

    // ---------- mask preload (vectorized; latency hides under barrier) ----------
    f32x4 mkv[7];
    {
        const float* mrow = mask + ((size_t)b * NG + (gok ? g : 0)) * NP;
        #pragma unroll
        for (int pt = 0; pt < 7; ++pt) {
            bool ld = gok && (pt < 6 || lh == 0);   // p+3 <= 99 only then
            mkv[pt] = ld ? *(const f32x4*)(mrow + pt * 16 + lh * 4)
                         : (f32x4){NINF, NINF, NINF, NINF};
        }
    }
    __syncthreads();

    // ---------- Phase 3: attention, all-register online path ----------
    short4v ocb[8];
    #pragma unroll
    for (int h = 0; h < NH; ++h) {
        float vals[7][4];
        #pragma unroll
        for (int pt = 0; pt < 7; ++pt) {
            short4v kf = *(const short4v*)(sK + (h * 7 + pt) * 256 + l16 * 16 + lh * 4);
            f32x4 z = {0.f, 0.f, 0.f, 0.f};
            f32x4 sc = mfma16(kf, qb[h], z);
            #pragma unroll
            for (int r = 0; r < 4; ++r)
                vals[pt][r] = sc[r] + mkv[pt][r];   // mkv = NINF at invalid (g,p)
        }
        float mr0 = vals[0][0], mr1 = vals[0][1], mr2 = vals[0][2], mr3 = vals[0][3];
        #pragma unroll
        for (int pt = 1; pt < 7; ++pt) {
            mr0 = fmaxf(mr0, vals[pt][0]); mr1 = fmaxf(mr1, vals[pt][1]);
            mr2 = fmaxf(mr2, vals[pt][2]); mr3 = fmaxf(mr3, vals[pt][3]);
        }
        float m = fmaxf(fmaxf(mr0, mr1), fmaxf(mr2, mr3));
        m = fmaxf(m, __shfl_xor(m, 16));
        m = fmaxf(m, __shfl_xor(m, 32));
        float s0 = 0.f, s1 = 0.f, s2 = 0.f, s3 = 0.f;
        #pragma unroll
        for (int pt = 0; pt < 7; ++pt) {
            float e0 = __expf(vals[pt][0] - m); vals[pt][0] = e0; s0 += e0;
            float e1 = __expf(vals[pt][1] - m); vals[pt][1] = e1; s1 += e1;
            float e2 = __expf(vals[pt][2] - m); vals[pt][2] = e2; s2 += e2;
            float e3 = __expf(vals[pt][3] - m); vals[pt][3] = e3; s3 += e3;
        }
        float s = (s0 + s1) + (s2 + s3);
        s += __shfl_xor(s, 16);
        s += __shfl_xor(s, 32);
        float inv = 1.f / s;
        f32x4 o0 = {0.f, 0.f, 0.f, 0.f}, o1 = {0.f, 0.f, 0.f, 0.f};
        #pragma unroll
        for (int pt = 0; pt < 7; ++pt) {
            short4v pb = { f2bf(vals[pt][0] * inv), f2bf(vals[pt][1] * inv),
                           f2bf(vals[pt][2] * inv), f2bf(vals[pt][3] * inv) };
            short4v vf = *(const short4v*)(sV + (h * 7 + pt) * 256 + l16 * 16 + lh * 4);
            if (pt & 1) o1 = mfma16(vf, pb, o1);
            else        o0 = mfma16(vf, pb, o0);
        }
        f32x4 o = o0 + o1;
        ocb[h] = (short4v){ f2bf(o[0]), f2bf(o[1]), f2bf(o[2]), f2bf(o[3]) };
    }

    // ---------- Phase 4: Mh^T = Wc^T . oc^T + bc, fold 1/sqrt(128) ----------
    short4v mhb[8];
    #pragma unroll
    for (int nt = 0; nt < 8; ++nt) {
        f32x4 acc0 = {0.f, 0.f, 0.f, 0.f}, acc1 = {0.f, 0.f, 0.f, 0.f};
        #pragma unroll
        for (int kt = 0; kt < 8; ++kt) {
            short4v a = *(const short4v*)(WcB + (nt * 8 + kt) * 256 + l16 * 16 + lh * 4);
            if (kt < 4) acc0 = mfma16(a, ocb[kt], acc0);
            else        acc1 = mfma16(a, ocb[kt], acc1);
        }
        f32x4 acc = acc0 + acc1;
        f32x4 bcv = *(const f32x4*)(bc + nt * 16 + lh * 4);
        mhb[nt] = (short4v){ f2bf((acc[0] + bcv[0]) * 0.08838834764831845f),
                             f2bf((acc[1] + bcv[1]) * 0.08838834764831845f),
                             f2bf((acc[2] + bcv[2]) * 0.08838834764831845f),
                             f2bf((acc[3] + bcv[3]) * 0.08838834764831845f) };
    }

    // ---------- Phase 5: pointer scores (enc frags from global f32) ----------
    const float* encb = enc + (size_t)b * NP * NE;
    const float* mrow = mask + ((size_t)b * NG + (gok ? g : 0)) * NP;
    float vals2[7][4];
    #pragma unroll
    for (int pt = 0; pt < 7; ++pt) {
        int prow = pt * 16 + l16;
        const float* erow = encb + (size_t)(prow < NP ? prow : NP - 1) * NE;
        f32x4 a0 = {0.f,0.f,0.f,0.f}, a1 = {0.f,0.f,0.f,0.f};
        #pragma unroll
        for (int kt = 0; kt < 8; ++kt) {
            f32x4 ev = *(const f32x4*)(erow + kt * 16 + lh * 4);
            short4v ef = { f2bf(ev[0]), f2bf(ev[1]), f2bf(ev[2]), f2bf(ev[3]) };
            if (kt < 4) a0 = mfma16(ef, mhb[kt], a0);
            else        a1 = mfma16(ef, mhb[kt], a1);
        }
        f32x4 acc = a0 + a1;
        bool ld = gok && (pt < 6 || lh == 0);
        f32x4 mv = ld ? *(const f32x4*)(mrow + pt * 16 + lh * 4)
                      : (f32x4){NINF, NINF, NINF, NINF};
        #pragma unroll
        for (int r = 0; r < 4; ++r) {
            float x = acc[r];                               // already scaled
            float th = 1.f - 2.f / (__expf(2.f * x) + 1.f); // tanh
            vals2[pt][r] = 10.f * th + mv[r];               // NINF at invalid (g,p)
        }
    }
    {
        float mr0 = vals2[0][0], mr1 = vals2[0][1], mr2 = vals2[0][2], mr3 = vals2[0][3];
        #pragma unroll
        for (int pt = 1; pt < 7; ++pt) {
            mr0 = fmaxf(mr0, vals2[pt][0]); mr1 = fmaxf(mr1, vals2[pt][1]);
            mr2 = fmaxf(mr2, vals2[pt][2]); mr3 = fmaxf(mr3, vals2[pt][3]);
        }
        float m = fmaxf(fmaxf(mr0, mr1), fmaxf(mr2, mr3));
        m = fmaxf(m, __shfl_xor(m, 16));
        m = fmaxf(m, __shfl_xor(m, 32));
        float s0 = 0.f, s1 = 0.f, s2 = 0.f, s3 = 0.f;
        #pragma unroll
        for (int pt = 0; pt < 7; ++pt) {
            float e0 = __expf(vals2[pt][0] - m); vals2[pt][0] = e0; s0 += e0;
            float e1 = __expf(vals2[pt][1] - m); vals2[pt][1] = e1; s1 += e1;
            float e2 = __expf(vals2[pt][2] - m); vals2[pt][2] = e2; s2 += e2;
            float e3 = __expf(vals2[pt][3] - m); vals2[pt][3] = e3; s3 += e3;
        }
        float s = (s0 + s1) + (s2 + s3);
        s += __shfl_xor(s, 16);
        s += __shfl_xor(s, 32);
        float inv = 1.f / s;
        float* orow = out + ((size_t)b * NG + g) * NP;
        #pragma unroll
        for (int pt = 0; pt < 7; ++pt) {
            bool st = gok && (pt < 6 || lh == 0);
            if (st) {
                f32x4 ov = { vals2[pt][0] * inv, vals2[pt][1] * inv,
                             vals2[pt][2] * inv, vals2[pt][3] * inv };
                *(f32x4*)(orow + pt * 16 + lh * 4) = ov;
            }
        }
    }
}

extern "C" void kernel_launch(void* const* d_in, const int* in_sizes, int n_in,
                              void* d_out, int out_size, void* d_ws, size_t ws_size,
                              hipStream_t stream)
{
    const float* input1 = (const float*)d_in[0];
    const float* input2 = (const float*)d_in[1];
    const float* rem    = (const float*)d_in[2];
    const float* mask   = (const float*)d_in[3];
    const float* enc    = (const float*)d_in[4];
    const float* Wq     = (const float*)d_in[5];
    const float* Wk     = (const float*)d_in[6];
    const float* Wv     = (const float*)d_in[7];
    const float* Wc     = (const float*)d_in[8];
    const float* bc     = (const float*)d_in[9];

    short* WqT2 = (short*)d_ws;
    short* WkT  = WqT2 + 16384;
    short* WvT  = WkT + 16384;
    short* WqT1 = WvT + 16384;
    short* WcB  = WqT1 + 16384;

    prep_kernel<<<320, 256, 0, stream>>>(Wq, Wk, Wv, Wc, WqT2, WkT, WvT, WqT1, WcB);

    fused_kernel<<<NB, 448, 0, stream>>>(
        input1, input2, rem, mask, enc, Wq, bc,
        WqT2, WkT, WvT, WqT1, WcB, (float*)d_out);
}